// Round 13
// baseline (75976.550 us; speedup 1.0000x reference)
//
#include <hip/hip_runtime.h>
#include <math.h>

// Problem constants (from setup_inputs)
#define NSEQ 8192
#define DH 512
#define DZ 128
#define DE 128
#define VOCAB 64
#define TMAX 80
#define SOS 1
#define EOS_TOK 2

#define BKK 16      // K-chunk for f64 MFMA GEMMs (32 chunks per 512-K)
#define TMR 64      // rows per block (4 waves x 16)
#define TNC 16      // cols per block per gate (1 MFMA col-tile; grid-y = 32)

typedef double d4 __attribute__((ext_vector_type(4)));

__device__ __forceinline__ float sigf(float x) { return 1.0f / (1.0f + expf(-x)); }
__device__ __forceinline__ int clamp15(int v) { return v < 0 ? 0 : (v > 15 ? 15 : v); }

// ---------------------------------------------------------------- MFMA C/D layout probe
__global__ __launch_bounds__(64) void probe_kernel(int* __restrict__ irow_map,
                                                   int* __restrict__ jcol_map) {
    __shared__ double As[16][17];
    __shared__ double Bs[4][17];
    const int lane = threadIdx.x;
    const int lrow = lane & 15, lq = lane >> 4;

    As[lrow][lq] = (lq == 0) ? (double)(lrow + 1) : 0.0;
    Bs[lq][lrow] = (lq == 0) ? 1.0 : 0.0;
    __syncthreads();
    d4 acc = {};
    acc = __builtin_amdgcn_mfma_f64_16x16x4f64(As[lrow][lq], Bs[lq][lrow], acc, 0, 0, 0);
#pragma unroll
    for (int r = 0; r < 4; ++r)
        irow_map[lane * 4 + r] = clamp15((int)(acc[r] + 0.5) - 1);
    __syncthreads();

    As[lrow][lq] = (lq == 0) ? 1.0 : 0.0;
    Bs[lq][lrow] = (lq == 0) ? (double)(lrow + 1) : 0.0;
    __syncthreads();
    d4 acc2 = {};
    acc2 = __builtin_amdgcn_mfma_f64_16x16x4f64(As[lrow][lq], Bs[lq][lrow], acc2, 0, 0, 0);
#pragma unroll
    for (int r = 0; r < 4; ++r)
        jcol_map[lane * 4 + r] = clamp15((int)(acc2[r] + 0.5) - 1);
}

// ---------------------------------------------------------------- init
__global__ __launch_bounds__(256) void init_kernel(int* __restrict__ x_prev,
                                                   int* __restrict__ eos,
                                                   int* __restrict__ out,
                                                   int* __restrict__ list,
                                                   int* __restrict__ count) {
    int i = blockIdx.x * 256 + threadIdx.x;
    x_prev[i] = SOS;
    eos[i] = 0;
    list[i] = i;
    out[i * TMAX] = SOS;
    out[NSEQ * TMAX + i] = TMAX;
    if (i == 0) count[0] = NSEQ;
}

// ---------------------------------------------------------------- active-row compaction
__global__ __launch_bounds__(1024) void compact_kernel(const int* __restrict__ eos,
                                                       int* __restrict__ list,
                                                       int* __restrict__ count) {
    __shared__ int part[1024];
    __shared__ int slist[NSEQ];
    const int tid = threadIdx.x;
    const int base = tid * 8;
    int f[8], s = 0;
#pragma unroll
    for (int i = 0; i < 8; ++i) { f[i] = eos[base + i] ? 0 : 1; s += f[i]; }
    part[tid] = s;
    __syncthreads();
    for (int off = 1; off < 1024; off <<= 1) {
        int v = (tid >= off) ? part[tid - off] : 0;
        __syncthreads();
        part[tid] += v;
        __syncthreads();
    }
    const int total = part[1023];
    int p = part[tid] - s;   // exclusive prefix
#pragma unroll
    for (int i = 0; i < 8; ++i) if (f[i]) slist[p++] = base + i;
    __syncthreads();
    if (tid == 0) {
        count[0] = total;
        if (total > 0) {
            const int last = slist[total - 1];
            const int padn = (total + 63) & ~63;
            for (int k = total; k < padn; ++k) slist[k] = last;
        }
    }
    __syncthreads();
    const int padn = (total + 63) & ~63;
    for (int k = tid; k < padn; k += 1024) list[k] = slist[k];
}

// ---------------------------------------------------------------- h0 = Z @ z2h_w.T + b (fp64 acc)
__global__ __launch_bounds__(256) void h0_kernel(const float* __restrict__ Z,
                                                 const float* __restrict__ w,
                                                 const float* __restrict__ b,
                                                 float* __restrict__ H0,
                                                 float* __restrict__ H1,
                                                 float* __restrict__ H2) {
    __shared__ float zrow[DZ];
    const int i = blockIdx.x;
    const int tid = threadIdx.x;
    if (tid < DZ) zrow[tid] = Z[(size_t)i * DZ + tid];
    __syncthreads();
    for (int j = tid; j < DH; j += 256) {
        double s = (double)b[j];
        const float* wr = w + (size_t)j * DZ;
#pragma unroll 8
        for (int k = 0; k < DZ; ++k) s += (double)zrow[k] * (double)wr[k];
        float sf = (float)s;
        size_t o = (size_t)i * DH + j;
        H0[o] = sf; H1[o] = sf; H2[o] = sf;
    }
}

// ---------------------------------------------------------------- gi0 table (fp64)
__global__ __launch_bounds__(256) void gi0_kernel(const float* __restrict__ emb,
                                                  const float* __restrict__ w_ih0,
                                                  const float* __restrict__ b_ih0,
                                                  double* __restrict__ tab) {
    __shared__ float e[DE];
    const int x = blockIdx.x;
    const int tid = threadIdx.x;
    if (tid < DE) e[tid] = emb[(size_t)x * DE + tid];
    __syncthreads();
    for (int j = tid; j < 3 * DH; j += 256) {
        double s = (double)b_ih0[j];
        const float* wr = w_ih0 + (size_t)j * DE;
#pragma unroll 8
        for (int k = 0; k < DE; ++k) s += (double)e[k] * (double)wr[k];
        tab[(size_t)x * 3 * DH + j] = s;
    }
}

// ---------------------------------------------------------------- layer 0: f64 MFMA GEMM, dbuf ping-pong + reg prefetch (TNC=16)
__global__ __launch_bounds__(256) void layer0_mfma(const float* __restrict__ Hc,
                                                   float* __restrict__ Hn,
                                                   const float* __restrict__ w_hh0,
                                                   const float* __restrict__ b_hh0,
                                                   const double* __restrict__ tab,
                                                   const int* __restrict__ x_prev,
                                                   const int* __restrict__ irow_map,
                                                   const int* __restrict__ jcol_map,
                                                   const int* __restrict__ list,
                                                   const int* __restrict__ count) {
    const int row0 = blockIdx.x * TMR;
    const int cnt = count[0];
    if (row0 >= cnt) return;

    __shared__ double As[2][TMR][BKK + 1];   // 2 x 8.5 KB
    __shared__ double Bs[2][BKK][48 + 2];    // 2 x 6.25 KB
    const int tid = threadIdx.x;
    const int lane = tid & 63, w = tid >> 6;
    const int lrow = lane & 15, lq = lane >> 4;
    const int col0 = blockIdx.y * TNC;

    int ir[4], jc[4];
    {
        const int4 a = *reinterpret_cast<const int4*>(&irow_map[lane * 4]);
        ir[0] = a.x; ir[1] = a.y; ir[2] = a.z; ir[3] = a.w;
        const int4 b = *reinterpret_cast<const int4*>(&jcol_map[lane * 4]);
        jc[0] = b.x; jc[1] = b.y; jc[2] = b.z; jc[3] = b.w;
    }

    const int ar = tid >> 2;          // A-stage row 0..63
    const int ak = (tid & 3) * 4;     // A-stage k offset {0,4,8,12}
    const float* __restrict__ Arow = Hc + (size_t)list[row0 + ar] * DH + ak;

    size_t bidx[3]; int bk_[3], bjr[3];
#pragma unroll
    for (int it = 0; it < 3; ++it) {
        const int e = it * 256 + tid;
        const int jr = e >> 4, k = e & 15;      // jr 0..47
        const int g = jr >> 4, c = jr & 15;
        bidx[it] = (size_t)(g * DH + col0 + c) * DH + k;
        bk_[it] = k; bjr[it] = jr;
    }

    d4 accR = {}, accZ = {}, accNH = {};

    float4 pa[2]; float pb[2][3];
    // chunk 0 -> regs slot 0 -> buf 0
    pa[0] = *reinterpret_cast<const float4*>(Arow);
#pragma unroll
    for (int it = 0; it < 3; ++it) pb[0][it] = w_hh0[bidx[it]];
    As[0][ar][ak + 0] = (double)pa[0].x; As[0][ar][ak + 1] = (double)pa[0].y;
    As[0][ar][ak + 2] = (double)pa[0].z; As[0][ar][ak + 3] = (double)pa[0].w;
#pragma unroll
    for (int it = 0; it < 3; ++it) Bs[0][bk_[it]][bjr[it]] = (double)pb[0][it];
    // chunk 1 -> regs slot 1 (in flight)
    pa[1] = *reinterpret_cast<const float4*>(Arow + BKK);
#pragma unroll
    for (int it = 0; it < 3; ++it) pb[1][it] = w_hh0[bidx[it] + BKK];
    __syncthreads();

    for (int kc = 0; kc < 32; ++kc) {
        const int cur = kc & 1, nxt = cur ^ 1;
        if (kc + 1 < 32) {   // stage chunk kc+1 -> buf nxt (safe: one barrier behind)
            As[nxt][ar][ak + 0] = (double)pa[nxt].x; As[nxt][ar][ak + 1] = (double)pa[nxt].y;
            As[nxt][ar][ak + 2] = (double)pa[nxt].z; As[nxt][ar][ak + 3] = (double)pa[nxt].w;
#pragma unroll
            for (int it = 0; it < 3; ++it) Bs[nxt][bk_[it]][bjr[it]] = (double)pb[nxt][it];
        }
        if (kc + 2 < 32) {   // load chunk kc+2 -> regs slot cur
            const int kn = (kc + 2) * BKK;
            pa[cur] = *reinterpret_cast<const float4*>(Arow + kn);
#pragma unroll
            for (int it = 0; it < 3; ++it) pb[cur][it] = w_hh0[bidx[it] + kn];
        }
        const double (*Ac)[BKK + 1] = As[cur];
        const double (*Bc)[50] = Bs[cur];
#pragma unroll
        for (int s = 0; s < 4; ++s) {
            const int kk = s * 4 + lq;
            const double a = Ac[w * 16 + lrow][kk];
            accR = __builtin_amdgcn_mfma_f64_16x16x4f64(a, Bc[kk][ 0 + lrow], accR, 0, 0, 0);
            accZ = __builtin_amdgcn_mfma_f64_16x16x4f64(a, Bc[kk][16 + lrow], accZ, 0, 0, 0);
            accNH = __builtin_amdgcn_mfma_f64_16x16x4f64(a, Bc[kk][32 + lrow], accNH, 0, 0, 0);
        }
        __syncthreads();
    }

#pragma unroll
    for (int reg = 0; reg < 4; ++reg) {
        const int gi = list[row0 + w * 16 + ir[reg]];
        const int gj = col0 + jc[reg];
        const double* tr = tab + (size_t)x_prev[gi] * 3 * DH;
        double xr = tr[gj] + accR[reg] + (double)b_hh0[gj];
        double xz = tr[DH + gj] + accZ[reg] + (double)b_hh0[DH + gj];
        double hn_pre = accNH[reg] + (double)b_hh0[2 * DH + gj];
        float r = sigf((float)xr);
        float z = sigf((float)xz);
        float g = tanhf((float)(tr[2 * DH + gj] + (double)r * hn_pre));
        float ho = Hc[(size_t)gi * DH + gj];
        Hn[(size_t)gi * DH + gj] = (1.0f - z) * g + z * ho;
    }
}

// ---------------------------------------------------------------- layers 1/2: f64 MFMA GEMM, dbuf ping-pong + reg prefetch (TNC=16)
__global__ __launch_bounds__(256) void layer12_mfma(const float* __restrict__ Xin,
                                                    const float* __restrict__ Hc,
                                                    float* __restrict__ Hn,
                                                    const float* __restrict__ w_ih,
                                                    const float* __restrict__ w_hh,
                                                    const float* __restrict__ b_ih,
                                                    const float* __restrict__ b_hh,
                                                    const int* __restrict__ irow_map,
                                                    const int* __restrict__ jcol_map,
                                                    const int* __restrict__ list,
                                                    const int* __restrict__ count) {
    const int row0 = blockIdx.x * TMR;
    const int cnt = count[0];
    if (row0 >= cnt) return;

    __shared__ double As[2][TMR][BKK + 1];
    __shared__ double Bs[2][BKK][48 + 2];
    const int tid = threadIdx.x;
    const int lane = tid & 63, w = tid >> 6;
    const int lrow = lane & 15, lq = lane >> 4;
    const int col0 = blockIdx.y * TNC;

    int ir[4], jc[4];
    {
        const int4 a = *reinterpret_cast<const int4*>(&irow_map[lane * 4]);
        ir[0] = a.x; ir[1] = a.y; ir[2] = a.z; ir[3] = a.w;
        const int4 b = *reinterpret_cast<const int4*>(&jcol_map[lane * 4]);
        jc[0] = b.x; jc[1] = b.y; jc[2] = b.z; jc[3] = b.w;
    }

    const int ar = tid >> 2;
    const int ak = (tid & 3) * 4;
    const size_t arow_off = (size_t)list[row0 + ar] * DH + ak;

    size_t bidx[3]; int bk_[3], bjr[3];
#pragma unroll
    for (int it = 0; it < 3; ++it) {
        const int e = it * 256 + tid;
        const int jr = e >> 4, k = e & 15;
        const int g = jr >> 4, c = jr & 15;
        bidx[it] = (size_t)(g * DH + col0 + c) * DH + k;
        bk_[it] = k; bjr[it] = jr;
    }

    d4 accR = {}, accZ = {}, accNI = {}, accNH = {};

    // flattened chunks: kc in [0,64); kc<32: Xin/w_ih, else Hc/w_hh; kb=(kc&31)*16
    float4 pa[2]; float pb[2][3];
    pa[0] = *reinterpret_cast<const float4*>(&Xin[arow_off]);
#pragma unroll
    for (int it = 0; it < 3; ++it) pb[0][it] = w_ih[bidx[it]];
    As[0][ar][ak + 0] = (double)pa[0].x; As[0][ar][ak + 1] = (double)pa[0].y;
    As[0][ar][ak + 2] = (double)pa[0].z; As[0][ar][ak + 3] = (double)pa[0].w;
#pragma unroll
    for (int it = 0; it < 3; ++it) Bs[0][bk_[it]][bjr[it]] = (double)pb[0][it];
    pa[1] = *reinterpret_cast<const float4*>(&Xin[arow_off + BKK]);
#pragma unroll
    for (int it = 0; it < 3; ++it) pb[1][it] = w_ih[bidx[it] + BKK];
    __syncthreads();

    for (int kc = 0; kc < 64; ++kc) {
        const int cur = kc & 1, nxt = cur ^ 1;
        if (kc + 1 < 64) {
            As[nxt][ar][ak + 0] = (double)pa[nxt].x; As[nxt][ar][ak + 1] = (double)pa[nxt].y;
            As[nxt][ar][ak + 2] = (double)pa[nxt].z; As[nxt][ar][ak + 3] = (double)pa[nxt].w;
#pragma unroll
            for (int it = 0; it < 3; ++it) Bs[nxt][bk_[it]][bjr[it]] = (double)pb[nxt][it];
        }
        if (kc + 2 < 64) {
            const int n = kc + 2;
            const float* __restrict__ An = (n < 32) ? Xin : Hc;
            const float* __restrict__ Wn = (n < 32) ? w_ih : w_hh;
            const int kbn = (n & 31) * BKK;
            pa[cur] = *reinterpret_cast<const float4*>(&An[arow_off + kbn]);
#pragma unroll
            for (int it = 0; it < 3; ++it) pb[cur][it] = Wn[bidx[it] + kbn];
        }
        const double (*Ac)[BKK + 1] = As[cur];
        const double (*Bc)[50] = Bs[cur];
        if (kc < 32) {
#pragma unroll
            for (int s = 0; s < 4; ++s) {
                const int kk = s * 4 + lq;
                const double a = Ac[w * 16 + lrow][kk];
                accR = __builtin_amdgcn_mfma_f64_16x16x4f64(a, Bc[kk][ 0 + lrow], accR, 0, 0, 0);
                accZ = __builtin_amdgcn_mfma_f64_16x16x4f64(a, Bc[kk][16 + lrow], accZ, 0, 0, 0);
                accNI = __builtin_amdgcn_mfma_f64_16x16x4f64(a, Bc[kk][32 + lrow], accNI, 0, 0, 0);
            }
        } else {
#pragma unroll
            for (int s = 0; s < 4; ++s) {
                const int kk = s * 4 + lq;
                const double a = Ac[w * 16 + lrow][kk];
                accR = __builtin_amdgcn_mfma_f64_16x16x4f64(a, Bc[kk][ 0 + lrow], accR, 0, 0, 0);
                accZ = __builtin_amdgcn_mfma_f64_16x16x4f64(a, Bc[kk][16 + lrow], accZ, 0, 0, 0);
                accNH = __builtin_amdgcn_mfma_f64_16x16x4f64(a, Bc[kk][32 + lrow], accNH, 0, 0, 0);
            }
        }
        __syncthreads();
    }

#pragma unroll
    for (int reg = 0; reg < 4; ++reg) {
        const int gi = list[row0 + w * 16 + ir[reg]];
        const int gj = col0 + jc[reg];
        double xr = accR[reg] + (double)b_ih[gj] + (double)b_hh[gj];
        double xz = accZ[reg] + (double)b_ih[DH + gj] + (double)b_hh[DH + gj];
        double xi = accNI[reg] + (double)b_ih[2 * DH + gj];
        double hn_pre = accNH[reg] + (double)b_hh[2 * DH + gj];
        float r = sigf((float)xr);
        float z = sigf((float)xz);
        float g = tanhf((float)(xi + (double)r * hn_pre));
        float ho = Hc[(size_t)gi * DH + gj];
        Hn[(size_t)gi * DH + gj] = (1.0f - z) * g + z * ho;
    }
}

// ---------------------------------------------------------------- logits + fp32 softmax + argmax + token update (row-indirect)
__global__ __launch_bounds__(256) void logits_kernel(const float* __restrict__ H2,
                                                     const float* __restrict__ h2v_w,
                                                     const float* __restrict__ h2v_b,
                                                     int* __restrict__ x_prev,
                                                     int* __restrict__ eos,
                                                     int* __restrict__ out,
                                                     const int* __restrict__ list,
                                                     const int* __restrict__ count,
                                                     int t) {
    const int rowbase = blockIdx.x * 16;
    const int cnt = count[0];
    if (rowbase >= cnt) return;

    __shared__ float Ws[VOCAB][65];
    __shared__ float Hs[16][65];
    const int tid = threadIdx.x;
    double acc[4] = {0.0, 0.0, 0.0, 0.0};

    for (int k0 = 0; k0 < DH; k0 += 64) {
        __syncthreads();
#pragma unroll
        for (int it = 0; it < 16; ++it) {
            int idx = tid + 256 * it;
            int v = idx >> 6, k = idx & 63;
            Ws[v][k] = h2v_w[(size_t)v * DH + k0 + k];
        }
#pragma unroll
        for (int it = 0; it < 4; ++it) {
            int idx = tid + 256 * it;
            int r = idx >> 6, k = idx & 63;
            Hs[r][k] = H2[(size_t)list[rowbase + r] * DH + k0 + k];
        }
        __syncthreads();
        const int r = tid >> 4;
        const int vb = (tid & 15) * 4;
#pragma unroll 16
        for (int k = 0; k < 64; ++k) {
            double h = (double)Hs[r][k];
            acc[0] += h * (double)Ws[vb + 0][k];
            acc[1] += h * (double)Ws[vb + 1][k];
            acc[2] += h * (double)Ws[vb + 2][k];
            acc[3] += h * (double)Ws[vb + 3][k];
        }
    }

    const int r = tid >> 4;
    const int vb = (tid & 15) * 4;
    float lf[4];
#pragma unroll
    for (int vv = 0; vv < 4; ++vv) lf[vv] = (float)(acc[vv] + (double)h2v_b[vb + vv]);

    float m = fmaxf(fmaxf(lf[0], lf[1]), fmaxf(lf[2], lf[3]));
#pragma unroll
    for (int off = 1; off < 16; off <<= 1) m = fmaxf(m, __shfl_xor(m, off));
    float e[4];
    float ssum = 0.f;
#pragma unroll
    for (int vv = 0; vv < 4; ++vv) { e[vv] = expf(lf[vv] - m); ssum += e[vv]; }
#pragma unroll
    for (int off = 1; off < 16; off <<= 1) ssum += __shfl_xor(ssum, off);

    float best = e[0] / ssum;
    int bi = vb;
#pragma unroll
    for (int vv = 1; vv < 4; ++vv) {
        float pv = e[vv] / ssum;
        if (pv > best) { best = pv; bi = vb + vv; }
    }
#pragma unroll
    for (int off = 1; off < 16; off <<= 1) {
        float ov = __shfl_xor(best, off);
        int oi = __shfl_xor(bi, off);
        if (ov > best || (ov == best && oi < bi)) { best = ov; bi = oi; }
    }
    if ((tid & 15) == 0) {
        const int gi = list[rowbase + r];
        const int ee = eos[gi];
        const int xt = bi;
        out[(size_t)gi * TMAX + t] = ee ? 0 : xt;
        if (!ee && xt == EOS_TOK) {
            out[NSEQ * TMAX + gi] = t + 1;
            eos[gi] = 1;
        }
        x_prev[gi] = xt;
    }
}

// ---------------------------------------------------------------- host
extern "C" void kernel_launch(void* const* d_in, const int* in_sizes, int n_in,
                              void* d_out, int out_size, void* d_ws, size_t ws_size,
                              hipStream_t stream) {
    const float* Z        = (const float*)d_in[0];
    const float* emb      = (const float*)d_in[1];
    const float* z2h_w    = (const float*)d_in[2];
    const float* z2h_b    = (const float*)d_in[3];
    const float* w_ih0    = (const float*)d_in[4];
    const float* w_ih_rest= (const float*)d_in[5];   // [2][1536][512]
    const float* w_hh     = (const float*)d_in[6];   // [3][1536][512]
    const float* b_ih     = (const float*)d_in[7];   // [3][1536]
    const float* b_hh     = (const float*)d_in[8];
    const float* h2v_w    = (const float*)d_in[9];
    const float* h2v_b    = (const float*)d_in[10];

    int* out = (int*)d_out;
    char* ws = (char*)d_ws;
    const size_t HB = (size_t)NSEQ * DH * sizeof(float);   // 16 MiB per H buffer
    float* B[4] = {(float*)ws, (float*)(ws + HB), (float*)(ws + 2 * HB), (float*)(ws + 3 * HB)};
    double* tab = (double*)(ws + 4 * HB);                  // [64][1536] fp64
    int* x_prev = (int*)(ws + 4 * HB + (size_t)VOCAB * 3 * DH * sizeof(double));
    int* eos    = x_prev + NSEQ;
    int* irow_map = eos + NSEQ;      // [64][4]
    int* jcol_map = irow_map + 256;  // [64][4]
    int* alist    = jcol_map + 256;  // [8192] active row list
    int* acount   = alist + NSEQ;    // [1]

    // PAD-fill the token region so skipped (post-EOS) rows read as PAD=0.
    hipMemsetAsync(out, 0, (size_t)NSEQ * TMAX * sizeof(int), stream);
    init_kernel<<<NSEQ / 256, 256, 0, stream>>>(x_prev, eos, out, alist, acount);
    probe_kernel<<<1, 64, 0, stream>>>(irow_map, jcol_map);
    h0_kernel<<<NSEQ, 256, 0, stream>>>(Z, z2h_w, z2h_b, B[0], B[1], B[2]);
    gi0_kernel<<<VOCAB, 256, 0, stream>>>(emb, w_ih0, b_ih, tab);

    const size_t WSTRIDE = (size_t)3 * DH * DH;   // 1536*512
    int c0 = 0, c1 = 1, c2 = 2, sp = 3;
    dim3 lgrid(NSEQ / TMR, DH / TNC);             // (128, 32)
    for (int t = 1; t < TMAX; ++t) {
        layer0_mfma<<<lgrid, 256, 0, stream>>>(B[c0], B[sp], w_hh, b_hh, tab, x_prev,
                                               irow_map, jcol_map, alist, acount);
        layer12_mfma<<<lgrid, 256, 0, stream>>>(B[sp], B[c1], B[c0],
            w_ih_rest, w_hh + WSTRIDE, b_ih + 3 * DH, b_hh + 3 * DH,
            irow_map, jcol_map, alist, acount);
        layer12_mfma<<<lgrid, 256, 0, stream>>>(B[c0], B[c2], B[c1],
            w_ih_rest + WSTRIDE, w_hh + 2 * WSTRIDE, b_ih + 6 * DH, b_hh + 6 * DH,
            irow_map, jcol_map, alist, acount);
        logits_kernel<<<NSEQ / 16, 256, 0, stream>>>(B[c1], h2v_w, h2v_b, x_prev, eos, out,
                                                     alist, acount, t);
        if (t < TMAX - 1)
            compact_kernel<<<1, 1024, 0, stream>>>(eos, alist, acount);
        int n0 = sp, n1 = c0, n2 = c1, nsp = c2;
        c0 = n0; c1 = n1; c2 = n2; sp = nsp;
    }
}

// Round 14
// 65074.384 us; speedup vs baseline: 1.1675x; 1.1675x over previous
//
#include <hip/hip_runtime.h>
#include <math.h>

// Problem constants (from setup_inputs)
#define NSEQ 8192
#define DH 512
#define DZ 128
#define DE 128
#define VOCAB 64
#define TMAX 80
#define SOS 1
#define EOS_TOK 2

#define BKK 16      // K-chunk for f64 MFMA GEMMs (32 chunks per 512-K)
#define TMR 64      // rows per block (4 waves x 16)
#define TNC 16      // cols per block per gate (1 MFMA col-tile; grid-y = 32)

typedef double d4 __attribute__((ext_vector_type(4)));

__device__ __forceinline__ float sigf(float x) { return 1.0f / (1.0f + expf(-x)); }
__device__ __forceinline__ int clamp15(int v) { return v < 0 ? 0 : (v > 15 ? 15 : v); }

// ---------------------------------------------------------------- MFMA C/D layout probe
__global__ __launch_bounds__(64) void probe_kernel(int* __restrict__ irow_map,
                                                   int* __restrict__ jcol_map) {
    __shared__ double As[16][17];
    __shared__ double Bs[4][17];
    const int lane = threadIdx.x;
    const int lrow = lane & 15, lq = lane >> 4;

    As[lrow][lq] = (lq == 0) ? (double)(lrow + 1) : 0.0;
    Bs[lq][lrow] = (lq == 0) ? 1.0 : 0.0;
    __syncthreads();
    d4 acc = {};
    acc = __builtin_amdgcn_mfma_f64_16x16x4f64(As[lrow][lq], Bs[lq][lrow], acc, 0, 0, 0);
#pragma unroll
    for (int r = 0; r < 4; ++r)
        irow_map[lane * 4 + r] = clamp15((int)(acc[r] + 0.5) - 1);
    __syncthreads();

    As[lrow][lq] = (lq == 0) ? 1.0 : 0.0;
    Bs[lq][lrow] = (lq == 0) ? (double)(lrow + 1) : 0.0;
    __syncthreads();
    d4 acc2 = {};
    acc2 = __builtin_amdgcn_mfma_f64_16x16x4f64(As[lrow][lq], Bs[lq][lrow], acc2, 0, 0, 0);
#pragma unroll
    for (int r = 0; r < 4; ++r)
        jcol_map[lane * 4 + r] = clamp15((int)(acc2[r] + 0.5) - 1);
}

// ---------------------------------------------------------------- init
__global__ __launch_bounds__(256) void init_kernel(int* __restrict__ x_prev,
                                                   int* __restrict__ eos,
                                                   int* __restrict__ out,
                                                   int* __restrict__ list,
                                                   int* __restrict__ count) {
    int i = blockIdx.x * 256 + threadIdx.x;
    x_prev[i] = SOS;
    eos[i] = 0;
    list[i] = i;
    out[i * TMAX] = SOS;
    out[NSEQ * TMAX + i] = TMAX;
    if (i == 0) count[0] = NSEQ;
}

// ---------------------------------------------------------------- active-row compaction
__global__ __launch_bounds__(1024) void compact_kernel(const int* __restrict__ eos,
                                                       int* __restrict__ list,
                                                       int* __restrict__ count) {
    __shared__ int part[1024];
    __shared__ int slist[NSEQ];
    const int tid = threadIdx.x;
    const int base = tid * 8;
    int f[8], s = 0;
#pragma unroll
    for (int i = 0; i < 8; ++i) { f[i] = eos[base + i] ? 0 : 1; s += f[i]; }
    part[tid] = s;
    __syncthreads();
    for (int off = 1; off < 1024; off <<= 1) {
        int v = (tid >= off) ? part[tid - off] : 0;
        __syncthreads();
        part[tid] += v;
        __syncthreads();
    }
    const int total = part[1023];
    int p = part[tid] - s;   // exclusive prefix
#pragma unroll
    for (int i = 0; i < 8; ++i) if (f[i]) slist[p++] = base + i;
    __syncthreads();
    if (tid == 0) {
        count[0] = total;
        if (total > 0) {
            const int last = slist[total - 1];
            const int padn = (total + 63) & ~63;
            for (int k = total; k < padn; ++k) slist[k] = last;
        }
    }
    __syncthreads();
    const int padn = (total + 63) & ~63;
    for (int k = tid; k < padn; k += 1024) list[k] = slist[k];
}

// ---------------------------------------------------------------- h0 = Z @ z2h_w.T + b (fp64 acc)
__global__ __launch_bounds__(256) void h0_kernel(const float* __restrict__ Z,
                                                 const float* __restrict__ w,
                                                 const float* __restrict__ b,
                                                 float* __restrict__ H0,
                                                 float* __restrict__ H1,
                                                 float* __restrict__ H2) {
    __shared__ float zrow[DZ];
    const int i = blockIdx.x;
    const int tid = threadIdx.x;
    if (tid < DZ) zrow[tid] = Z[(size_t)i * DZ + tid];
    __syncthreads();
    for (int j = tid; j < DH; j += 256) {
        double s = (double)b[j];
        const float* wr = w + (size_t)j * DZ;
#pragma unroll 8
        for (int k = 0; k < DZ; ++k) s += (double)zrow[k] * (double)wr[k];
        float sf = (float)s;
        size_t o = (size_t)i * DH + j;
        H0[o] = sf; H1[o] = sf; H2[o] = sf;
    }
}

// ---------------------------------------------------------------- gi0 table (fp64)
__global__ __launch_bounds__(256) void gi0_kernel(const float* __restrict__ emb,
                                                  const float* __restrict__ w_ih0,
                                                  const float* __restrict__ b_ih0,
                                                  double* __restrict__ tab) {
    __shared__ float e[DE];
    const int x = blockIdx.x;
    const int tid = threadIdx.x;
    if (tid < DE) e[tid] = emb[(size_t)x * DE + tid];
    __syncthreads();
    for (int j = tid; j < 3 * DH; j += 256) {
        double s = (double)b_ih0[j];
        const float* wr = w_ih0 + (size_t)j * DE;
#pragma unroll 8
        for (int k = 0; k < DE; ++k) s += (double)e[k] * (double)wr[k];
        tab[(size_t)x * 3 * DH + j] = s;
    }
}

// ---------------------------------------------------------------- layer 0: f64 MFMA GEMM, register-pipelined, row-indirect
// __launch_bounds__(256,5): cap VGPR at 102 -> 5 blocks/CU (20 waves) for latency hiding
__global__ __launch_bounds__(256, 5) void layer0_mfma(const float* __restrict__ Hc,
                                                      float* __restrict__ Hn,
                                                      const float* __restrict__ w_hh0,
                                                      const float* __restrict__ b_hh0,
                                                      const double* __restrict__ tab,
                                                      const int* __restrict__ x_prev,
                                                      const int* __restrict__ irow_map,
                                                      const int* __restrict__ jcol_map,
                                                      const int* __restrict__ list,
                                                      const int* __restrict__ count) {
    const int row0 = blockIdx.x * TMR;
    const int cnt = count[0];
    if (row0 >= cnt) return;

    __shared__ double As[TMR][BKK + 1];   // [64][17]
    __shared__ double Bs[BKK][48 + 2];    // [16][50]
    const int tid = threadIdx.x;
    const int lane = tid & 63, w = tid >> 6;
    const int lrow = lane & 15, lq = lane >> 4;
    const int col0 = blockIdx.y * TNC;

    int ir[4], jc[4];
    {
        const int4 a = *reinterpret_cast<const int4*>(&irow_map[lane * 4]);
        ir[0] = a.x; ir[1] = a.y; ir[2] = a.z; ir[3] = a.w;
        const int4 b = *reinterpret_cast<const int4*>(&jcol_map[lane * 4]);
        jc[0] = b.x; jc[1] = b.y; jc[2] = b.z; jc[3] = b.w;
    }

    const int ar = tid >> 2;          // A-stage row 0..63
    const int ak = (tid & 3) * 4;     // A-stage k offset {0,4,8,12}
    const int arow_g = list[row0 + ar];
    const float* __restrict__ Arow = Hc + (size_t)arow_g * DH + ak;

    // B staging: 48 rows x 16 k = 768 elems, 3 per thread
    size_t bidx[3]; int bk_[3], bjr[3];
#pragma unroll
    for (int it = 0; it < 3; ++it) {
        const int e = it * 256 + tid;
        const int jr = e >> 4, k = e & 15;      // jr 0..47
        const int g = jr >> 4, c = jr & 15;     // gate, col
        bidx[it] = (size_t)(g * DH + col0 + c) * DH + k;
        bk_[it] = k; bjr[it] = jr;
    }

    d4 accR = {}, accZ = {}, accNH = {};

    float4 pa = *reinterpret_cast<const float4*>(Arow);
    float pb[3];
#pragma unroll
    for (int it = 0; it < 3; ++it) pb[it] = w_hh0[bidx[it]];

    for (int kc = 0; kc < 32; ++kc) {
        __syncthreads();
        As[ar][ak + 0] = (double)pa.x; As[ar][ak + 1] = (double)pa.y;
        As[ar][ak + 2] = (double)pa.z; As[ar][ak + 3] = (double)pa.w;
#pragma unroll
        for (int it = 0; it < 3; ++it) Bs[bk_[it]][bjr[it]] = (double)pb[it];
        __syncthreads();

        if (kc < 31) {
            const int kn = (kc + 1) * BKK;
            pa = *reinterpret_cast<const float4*>(Arow + kn);
#pragma unroll
            for (int it = 0; it < 3; ++it) pb[it] = w_hh0[bidx[it] + kn];
        }

#pragma unroll
        for (int s = 0; s < 4; ++s) {
            const int kk = s * 4 + lq;
            const double a = As[w * 16 + lrow][kk];
            accR = __builtin_amdgcn_mfma_f64_16x16x4f64(a, Bs[kk][ 0 + lrow], accR, 0, 0, 0);
            accZ = __builtin_amdgcn_mfma_f64_16x16x4f64(a, Bs[kk][16 + lrow], accZ, 0, 0, 0);
            accNH = __builtin_amdgcn_mfma_f64_16x16x4f64(a, Bs[kk][32 + lrow], accNH, 0, 0, 0);
        }
    }

#pragma unroll
    for (int reg = 0; reg < 4; ++reg) {
        const int gi = list[row0 + w * 16 + ir[reg]];
        const int gj = col0 + jc[reg];
        const double* tr = tab + (size_t)x_prev[gi] * 3 * DH;
        double xr = tr[gj] + accR[reg] + (double)b_hh0[gj];
        double xz = tr[DH + gj] + accZ[reg] + (double)b_hh0[DH + gj];
        double hn_pre = accNH[reg] + (double)b_hh0[2 * DH + gj];
        float r = sigf((float)xr);
        float z = sigf((float)xz);
        float g = tanhf((float)(tr[2 * DH + gj] + (double)r * hn_pre));
        float ho = Hc[(size_t)gi * DH + gj];
        Hn[(size_t)gi * DH + gj] = (1.0f - z) * g + z * ho;
    }
}

// ---------------------------------------------------------------- layers 1/2: f64 MFMA GEMM, register-pipelined, row-indirect
__global__ __launch_bounds__(256, 5) void layer12_mfma(const float* __restrict__ Xin,
                                                       const float* __restrict__ Hc,
                                                       float* __restrict__ Hn,
                                                       const float* __restrict__ w_ih,
                                                       const float* __restrict__ w_hh,
                                                       const float* __restrict__ b_ih,
                                                       const float* __restrict__ b_hh,
                                                       const int* __restrict__ irow_map,
                                                       const int* __restrict__ jcol_map,
                                                       const int* __restrict__ list,
                                                       const int* __restrict__ count) {
    const int row0 = blockIdx.x * TMR;
    const int cnt = count[0];
    if (row0 >= cnt) return;

    __shared__ double As[TMR][BKK + 1];
    __shared__ double Bs[BKK][48 + 2];
    const int tid = threadIdx.x;
    const int lane = tid & 63, w = tid >> 6;
    const int lrow = lane & 15, lq = lane >> 4;
    const int col0 = blockIdx.y * TNC;

    int ir[4], jc[4];
    {
        const int4 a = *reinterpret_cast<const int4*>(&irow_map[lane * 4]);
        ir[0] = a.x; ir[1] = a.y; ir[2] = a.z; ir[3] = a.w;
        const int4 b = *reinterpret_cast<const int4*>(&jcol_map[lane * 4]);
        jc[0] = b.x; jc[1] = b.y; jc[2] = b.z; jc[3] = b.w;
    }

    const int ar = tid >> 2;
    const int ak = (tid & 3) * 4;
    const int arow_g = list[row0 + ar];
    const size_t arow_off = (size_t)arow_g * DH + ak;

    size_t bidx[3]; int bk_[3], bjr[3];
#pragma unroll
    for (int it = 0; it < 3; ++it) {
        const int e = it * 256 + tid;
        const int jr = e >> 4, k = e & 15;
        const int g = jr >> 4, c = jr & 15;
        bidx[it] = (size_t)(g * DH + col0 + c) * DH + k;
        bk_[it] = k; bjr[it] = jr;
    }

    d4 accR = {}, accZ = {}, accNI = {}, accNH = {};

    float4 pa = *reinterpret_cast<const float4*>(&Xin[arow_off]);
    float pb[3];
#pragma unroll
    for (int it = 0; it < 3; ++it) pb[it] = w_ih[bidx[it]];

    for (int kc2 = 0; kc2 < 64; ++kc2) {
        __syncthreads();
        As[ar][ak + 0] = (double)pa.x; As[ar][ak + 1] = (double)pa.y;
        As[ar][ak + 2] = (double)pa.z; As[ar][ak + 3] = (double)pa.w;
#pragma unroll
        for (int it = 0; it < 3; ++it) Bs[bk_[it]][bjr[it]] = (double)pb[it];
        __syncthreads();

        if (kc2 < 63) {
            const int n = kc2 + 1;
            const float* __restrict__ An = (n < 32) ? Xin : Hc;
            const float* __restrict__ Wn = (n < 32) ? w_ih : w_hh;
            const int kbn = (n & 31) * BKK;
            pa = *reinterpret_cast<const float4*>(&An[arow_off + kbn]);
#pragma unroll
            for (int it = 0; it < 3; ++it) pb[it] = Wn[bidx[it] + kbn];
        }

        if (kc2 < 32) {
#pragma unroll
            for (int s = 0; s < 4; ++s) {
                const int kk = s * 4 + lq;
                const double a = As[w * 16 + lrow][kk];
                accR = __builtin_amdgcn_mfma_f64_16x16x4f64(a, Bs[kk][ 0 + lrow], accR, 0, 0, 0);
                accZ = __builtin_amdgcn_mfma_f64_16x16x4f64(a, Bs[kk][16 + lrow], accZ, 0, 0, 0);
                accNI = __builtin_amdgcn_mfma_f64_16x16x4f64(a, Bs[kk][32 + lrow], accNI, 0, 0, 0);
            }
        } else {
#pragma unroll
            for (int s = 0; s < 4; ++s) {
                const int kk = s * 4 + lq;
                const double a = As[w * 16 + lrow][kk];
                accR = __builtin_amdgcn_mfma_f64_16x16x4f64(a, Bs[kk][ 0 + lrow], accR, 0, 0, 0);
                accZ = __builtin_amdgcn_mfma_f64_16x16x4f64(a, Bs[kk][16 + lrow], accZ, 0, 0, 0);
                accNH = __builtin_amdgcn_mfma_f64_16x16x4f64(a, Bs[kk][32 + lrow], accNH, 0, 0, 0);
            }
        }
    }

#pragma unroll
    for (int reg = 0; reg < 4; ++reg) {
        const int gi = list[row0 + w * 16 + ir[reg]];
        const int gj = col0 + jc[reg];
        double xr = accR[reg] + (double)b_ih[gj] + (double)b_hh[gj];
        double xz = accZ[reg] + (double)b_ih[DH + gj] + (double)b_hh[DH + gj];
        double xi = accNI[reg] + (double)b_ih[2 * DH + gj];
        double hn_pre = accNH[reg] + (double)b_hh[2 * DH + gj];
        float r = sigf((float)xr);
        float z = sigf((float)xz);
        float g = tanhf((float)(xi + (double)r * hn_pre));
        float ho = Hc[(size_t)gi * DH + gj];
        Hn[(size_t)gi * DH + gj] = (1.0f - z) * g + z * ho;
    }
}

// ---------------------------------------------------------------- logits + fp32 softmax + argmax + token update (row-indirect)
__global__ __launch_bounds__(256) void logits_kernel(const float* __restrict__ H2,
                                                     const float* __restrict__ h2v_w,
                                                     const float* __restrict__ h2v_b,
                                                     int* __restrict__ x_prev,
                                                     int* __restrict__ eos,
                                                     int* __restrict__ out,
                                                     const int* __restrict__ list,
                                                     const int* __restrict__ count,
                                                     int t) {
    const int rowbase = blockIdx.x * 16;
    const int cnt = count[0];
    if (rowbase >= cnt) return;

    __shared__ float Ws[VOCAB][65];
    __shared__ float Hs[16][65];
    const int tid = threadIdx.x;
    double acc[4] = {0.0, 0.0, 0.0, 0.0};

    for (int k0 = 0; k0 < DH; k0 += 64) {
        __syncthreads();
#pragma unroll
        for (int it = 0; it < 16; ++it) {
            int idx = tid + 256 * it;
            int v = idx >> 6, k = idx & 63;
            Ws[v][k] = h2v_w[(size_t)v * DH + k0 + k];
        }
#pragma unroll
        for (int it = 0; it < 4; ++it) {
            int idx = tid + 256 * it;
            int r = idx >> 6, k = idx & 63;
            Hs[r][k] = H2[(size_t)list[rowbase + r] * DH + k0 + k];
        }
        __syncthreads();
        const int r = tid >> 4;
        const int vb = (tid & 15) * 4;
#pragma unroll 16
        for (int k = 0; k < 64; ++k) {
            double h = (double)Hs[r][k];
            acc[0] += h * (double)Ws[vb + 0][k];
            acc[1] += h * (double)Ws[vb + 1][k];
            acc[2] += h * (double)Ws[vb + 2][k];
            acc[3] += h * (double)Ws[vb + 3][k];
        }
    }

    const int r = tid >> 4;
    const int vb = (tid & 15) * 4;
    float lf[4];
#pragma unroll
    for (int vv = 0; vv < 4; ++vv) lf[vv] = (float)(acc[vv] + (double)h2v_b[vb + vv]);

    float m = fmaxf(fmaxf(lf[0], lf[1]), fmaxf(lf[2], lf[3]));
#pragma unroll
    for (int off = 1; off < 16; off <<= 1) m = fmaxf(m, __shfl_xor(m, off));
    float e[4];
    float ssum = 0.f;
#pragma unroll
    for (int vv = 0; vv < 4; ++vv) { e[vv] = expf(lf[vv] - m); ssum += e[vv]; }
#pragma unroll
    for (int off = 1; off < 16; off <<= 1) ssum += __shfl_xor(ssum, off);

    float best = e[0] / ssum;
    int bi = vb;
#pragma unroll
    for (int vv = 1; vv < 4; ++vv) {
        float pv = e[vv] / ssum;
        if (pv > best) { best = pv; bi = vb + vv; }
    }
#pragma unroll
    for (int off = 1; off < 16; off <<= 1) {
        float ov = __shfl_xor(best, off);
        int oi = __shfl_xor(bi, off);
        if (ov > best || (ov == best && oi < bi)) { best = ov; bi = oi; }
    }
    if ((tid & 15) == 0) {
        const int gi = list[rowbase + r];
        const int ee = eos[gi];
        const int xt = bi;
        out[(size_t)gi * TMAX + t] = ee ? 0 : xt;
        if (!ee && xt == EOS_TOK) {
            out[NSEQ * TMAX + gi] = t + 1;
            eos[gi] = 1;
        }
        x_prev[gi] = xt;
    }
}

// ---------------------------------------------------------------- host
extern "C" void kernel_launch(void* const* d_in, const int* in_sizes, int n_in,
                              void* d_out, int out_size, void* d_ws, size_t ws_size,
                              hipStream_t stream) {
    const float* Z        = (const float*)d_in[0];
    const float* emb      = (const float*)d_in[1];
    const float* z2h_w    = (const float*)d_in[2];
    const float* z2h_b    = (const float*)d_in[3];
    const float* w_ih0    = (const float*)d_in[4];
    const float* w_ih_rest= (const float*)d_in[5];   // [2][1536][512]
    const float* w_hh     = (const float*)d_in[6];   // [3][1536][512]
    const float* b_ih     = (const float*)d_in[7];   // [3][1536]
    const float* b_hh     = (const float*)d_in[8];
    const float* h2v_w    = (const float*)d_in[9];
    const float* h2v_b    = (const float*)d_in[10];

    int* out = (int*)d_out;
    char* ws = (char*)d_ws;
    const size_t HB = (size_t)NSEQ * DH * sizeof(float);   // 16 MiB per H buffer
    float* B[4] = {(float*)ws, (float*)(ws + HB), (float*)(ws + 2 * HB), (float*)(ws + 3 * HB)};
    double* tab = (double*)(ws + 4 * HB);                  // [64][1536] fp64
    int* x_prev = (int*)(ws + 4 * HB + (size_t)VOCAB * 3 * DH * sizeof(double));
    int* eos    = x_prev + NSEQ;
    int* irow_map = eos + NSEQ;      // [64][4]
    int* jcol_map = irow_map + 256;  // [64][4]
    int* alist    = jcol_map + 256;  // [8192] active row list
    int* acount   = alist + NSEQ;    // [1]

    // PAD-fill the token region so skipped (post-EOS) rows read as PAD=0.
    hipMemsetAsync(out, 0, (size_t)NSEQ * TMAX * sizeof(int), stream);
    init_kernel<<<NSEQ / 256, 256, 0, stream>>>(x_prev, eos, out, alist, acount);
    probe_kernel<<<1, 64, 0, stream>>>(irow_map, jcol_map);
    h0_kernel<<<NSEQ, 256, 0, stream>>>(Z, z2h_w, z2h_b, B[0], B[1], B[2]);
    gi0_kernel<<<VOCAB, 256, 0, stream>>>(emb, w_ih0, b_ih, tab);

    const size_t WSTRIDE = (size_t)3 * DH * DH;   // 1536*512
    int c0 = 0, c1 = 1, c2 = 2, sp = 3;
    dim3 lgrid(NSEQ / TMR, DH / TNC);             // (128, 32)
    for (int t = 1; t < TMAX; ++t) {
        layer0_mfma<<<lgrid, 256, 0, stream>>>(B[c0], B[sp], w_hh, b_hh, tab, x_prev,
                                               irow_map, jcol_map, alist, acount);
        layer12_mfma<<<lgrid, 256, 0, stream>>>(B[sp], B[c1], B[c0],
            w_ih_rest, w_hh + WSTRIDE, b_ih + 3 * DH, b_hh + 3 * DH,
            irow_map, jcol_map, alist, acount);
        layer12_mfma<<<lgrid, 256, 0, stream>>>(B[c0], B[c2], B[c1],
            w_ih_rest + WSTRIDE, w_hh + 2 * WSTRIDE, b_ih + 6 * DH, b_hh + 6 * DH,
            irow_map, jcol_map, alist, acount);
        logits_kernel<<<NSEQ / 16, 256, 0, stream>>>(B[c1], h2v_w, h2v_b, x_prev, eos, out,
                                                     alist, acount, t);
        if (t < TMAX - 1)
            compact_kernel<<<1, 1024, 0, stream>>>(eos, alist, acount);
        int n0 = sp, n1 = c0, n2 = c1, nsp = c2;
        c0 = n0; c1 = n1; c2 = n2; sp = nsp;
    }
}

// Round 15
// 64351.587 us; speedup vs baseline: 1.1806x; 1.0112x over previous
//
#include <hip/hip_runtime.h>
#include <math.h>

// Problem constants (from setup_inputs)
#define NSEQ 8192
#define DH 512
#define DZ 128
#define DE 128
#define VOCAB 64
#define TMAX 80
#define SOS 1
#define EOS_TOK 2

#define BKK 16      // K-chunk for f64 MFMA GEMMs (32 chunks per 512-K)
#define TMR 64      // rows per block (4 waves x 16)
#define TNC 16      // cols per block per gate (1 MFMA col-tile; 32 col-tiles)

typedef double d4 __attribute__((ext_vector_type(4)));

__device__ __forceinline__ float sigf(float x) { return 1.0f / (1.0f + expf(-x)); }
__device__ __forceinline__ int clamp15(int v) { return v < 0 ? 0 : (v > 15 ? 15 : v); }

// XCD-aware swizzle: bid -> (row-tile, col-tile). Consecutive bids round-robin
// XCDs (heuristic); this maps all col-tiles of a row-tile onto one XCD (A-rows
// L2-resident) and groups same-col blocks consecutively (B-rows shared in L2).
// Bijective over [0, 128*32). Pure locality play: correctness-neutral.
__device__ __forceinline__ void swizzle_rc(int bid, int& r, int& c) {
    const int x = bid & 7;
    const int q = bid >> 3;       // 0..511
    r = (q & 15) * 8 + x;         // 0..127
    c = q >> 4;                   // 0..31
}

// ---------------------------------------------------------------- MFMA C/D layout probe
__global__ __launch_bounds__(64) void probe_kernel(int* __restrict__ irow_map,
                                                   int* __restrict__ jcol_map) {
    __shared__ double As[16][17];
    __shared__ double Bs[4][17];
    const int lane = threadIdx.x;
    const int lrow = lane & 15, lq = lane >> 4;

    As[lrow][lq] = (lq == 0) ? (double)(lrow + 1) : 0.0;
    Bs[lq][lrow] = (lq == 0) ? 1.0 : 0.0;
    __syncthreads();
    d4 acc = {};
    acc = __builtin_amdgcn_mfma_f64_16x16x4f64(As[lrow][lq], Bs[lq][lrow], acc, 0, 0, 0);
#pragma unroll
    for (int r = 0; r < 4; ++r)
        irow_map[lane * 4 + r] = clamp15((int)(acc[r] + 0.5) - 1);
    __syncthreads();

    As[lrow][lq] = (lq == 0) ? 1.0 : 0.0;
    Bs[lq][lrow] = (lq == 0) ? (double)(lrow + 1) : 0.0;
    __syncthreads();
    d4 acc2 = {};
    acc2 = __builtin_amdgcn_mfma_f64_16x16x4f64(As[lrow][lq], Bs[lq][lrow], acc2, 0, 0, 0);
#pragma unroll
    for (int r = 0; r < 4; ++r)
        jcol_map[lane * 4 + r] = clamp15((int)(acc2[r] + 0.5) - 1);
}

// ---------------------------------------------------------------- init
__global__ __launch_bounds__(256) void init_kernel(int* __restrict__ x_prev,
                                                   int* __restrict__ eos,
                                                   int* __restrict__ out,
                                                   int* __restrict__ list,
                                                   int* __restrict__ count) {
    int i = blockIdx.x * 256 + threadIdx.x;
    x_prev[i] = SOS;
    eos[i] = 0;
    list[i] = i;
    out[i * TMAX] = SOS;
    out[NSEQ * TMAX + i] = TMAX;
    if (i == 0) count[0] = NSEQ;
}

// ---------------------------------------------------------------- active-row compaction
__global__ __launch_bounds__(1024) void compact_kernel(const int* __restrict__ eos,
                                                       int* __restrict__ list,
                                                       int* __restrict__ count) {
    __shared__ int part[1024];
    __shared__ int slist[NSEQ];
    const int tid = threadIdx.x;
    const int base = tid * 8;
    int f[8], s = 0;
#pragma unroll
    for (int i = 0; i < 8; ++i) { f[i] = eos[base + i] ? 0 : 1; s += f[i]; }
    part[tid] = s;
    __syncthreads();
    for (int off = 1; off < 1024; off <<= 1) {
        int v = (tid >= off) ? part[tid - off] : 0;
        __syncthreads();
        part[tid] += v;
        __syncthreads();
    }
    const int total = part[1023];
    int p = part[tid] - s;   // exclusive prefix
#pragma unroll
    for (int i = 0; i < 8; ++i) if (f[i]) slist[p++] = base + i;
    __syncthreads();
    if (tid == 0) {
        count[0] = total;
        if (total > 0) {
            const int last = slist[total - 1];
            const int padn = (total + 63) & ~63;
            for (int k = total; k < padn; ++k) slist[k] = last;
        }
    }
    __syncthreads();
    const int padn = (total + 63) & ~63;
    for (int k = tid; k < padn; k += 1024) list[k] = slist[k];
}

// ---------------------------------------------------------------- h0 = Z @ z2h_w.T + b (fp64 acc)
__global__ __launch_bounds__(256) void h0_kernel(const float* __restrict__ Z,
                                                 const float* __restrict__ w,
                                                 const float* __restrict__ b,
                                                 float* __restrict__ H0,
                                                 float* __restrict__ H1,
                                                 float* __restrict__ H2) {
    __shared__ float zrow[DZ];
    const int i = blockIdx.x;
    const int tid = threadIdx.x;
    if (tid < DZ) zrow[tid] = Z[(size_t)i * DZ + tid];
    __syncthreads();
    for (int j = tid; j < DH; j += 256) {
        double s = (double)b[j];
        const float* wr = w + (size_t)j * DZ;
#pragma unroll 8
        for (int k = 0; k < DZ; ++k) s += (double)zrow[k] * (double)wr[k];
        float sf = (float)s;
        size_t o = (size_t)i * DH + j;
        H0[o] = sf; H1[o] = sf; H2[o] = sf;
    }
}

// ---------------------------------------------------------------- gi0 table (fp64)
__global__ __launch_bounds__(256) void gi0_kernel(const float* __restrict__ emb,
                                                  const float* __restrict__ w_ih0,
                                                  const float* __restrict__ b_ih0,
                                                  double* __restrict__ tab) {
    __shared__ float e[DE];
    const int x = blockIdx.x;
    const int tid = threadIdx.x;
    if (tid < DE) e[tid] = emb[(size_t)x * DE + tid];
    __syncthreads();
    for (int j = tid; j < 3 * DH; j += 256) {
        double s = (double)b_ih0[j];
        const float* wr = w_ih0 + (size_t)j * DE;
#pragma unroll 8
        for (int k = 0; k < DE; ++k) s += (double)e[k] * (double)wr[k];
        tab[(size_t)x * 3 * DH + j] = s;
    }
}

// ---------------------------------------------------------------- layer 0: f64 MFMA GEMM, register-pipelined, row-indirect, swizzled
__global__ __launch_bounds__(256, 5) void layer0_mfma(const float* __restrict__ Hc,
                                                      float* __restrict__ Hn,
                                                      const float* __restrict__ w_hh0,
                                                      const float* __restrict__ b_hh0,
                                                      const double* __restrict__ tab,
                                                      const int* __restrict__ x_prev,
                                                      const int* __restrict__ irow_map,
                                                      const int* __restrict__ jcol_map,
                                                      const int* __restrict__ list,
                                                      const int* __restrict__ count) {
    int rt, ct_;
    swizzle_rc(blockIdx.x, rt, ct_);
    const int row0 = rt * TMR;
    const int cnt = count[0];
    if (row0 >= cnt) return;
    const int col0 = ct_ * TNC;

    __shared__ double As[TMR][BKK + 1];   // [64][17]
    __shared__ double Bs[BKK][48 + 2];    // [16][50]
    const int tid = threadIdx.x;
    const int lane = tid & 63, w = tid >> 6;
    const int lrow = lane & 15, lq = lane >> 4;

    int ir[4], jc[4];
    {
        const int4 a = *reinterpret_cast<const int4*>(&irow_map[lane * 4]);
        ir[0] = a.x; ir[1] = a.y; ir[2] = a.z; ir[3] = a.w;
        const int4 b = *reinterpret_cast<const int4*>(&jcol_map[lane * 4]);
        jc[0] = b.x; jc[1] = b.y; jc[2] = b.z; jc[3] = b.w;
    }

    const int ar = tid >> 2;          // A-stage row 0..63
    const int ak = (tid & 3) * 4;     // A-stage k offset {0,4,8,12}
    const int arow_g = list[row0 + ar];
    const float* __restrict__ Arow = Hc + (size_t)arow_g * DH + ak;

    // B staging: 48 rows x 16 k = 768 elems, 3 per thread
    size_t bidx[3]; int bk_[3], bjr[3];
#pragma unroll
    for (int it = 0; it < 3; ++it) {
        const int e = it * 256 + tid;
        const int jr = e >> 4, k = e & 15;      // jr 0..47
        const int g = jr >> 4, c = jr & 15;     // gate, col
        bidx[it] = (size_t)(g * DH + col0 + c) * DH + k;
        bk_[it] = k; bjr[it] = jr;
    }

    d4 accR = {}, accZ = {}, accNH = {};

    float4 pa = *reinterpret_cast<const float4*>(Arow);
    float pb[3];
#pragma unroll
    for (int it = 0; it < 3; ++it) pb[it] = w_hh0[bidx[it]];

    for (int kc = 0; kc < 32; ++kc) {
        __syncthreads();
        As[ar][ak + 0] = (double)pa.x; As[ar][ak + 1] = (double)pa.y;
        As[ar][ak + 2] = (double)pa.z; As[ar][ak + 3] = (double)pa.w;
#pragma unroll
        for (int it = 0; it < 3; ++it) Bs[bk_[it]][bjr[it]] = (double)pb[it];
        __syncthreads();

        if (kc < 31) {
            const int kn = (kc + 1) * BKK;
            pa = *reinterpret_cast<const float4*>(Arow + kn);
#pragma unroll
            for (int it = 0; it < 3; ++it) pb[it] = w_hh0[bidx[it] + kn];
        }

#pragma unroll
        for (int s = 0; s < 4; ++s) {
            const int kk = s * 4 + lq;
            const double a = As[w * 16 + lrow][kk];
            accR = __builtin_amdgcn_mfma_f64_16x16x4f64(a, Bs[kk][ 0 + lrow], accR, 0, 0, 0);
            accZ = __builtin_amdgcn_mfma_f64_16x16x4f64(a, Bs[kk][16 + lrow], accZ, 0, 0, 0);
            accNH = __builtin_amdgcn_mfma_f64_16x16x4f64(a, Bs[kk][32 + lrow], accNH, 0, 0, 0);
        }
    }

#pragma unroll
    for (int reg = 0; reg < 4; ++reg) {
        const int gi = list[row0 + w * 16 + ir[reg]];
        const int gj = col0 + jc[reg];
        const double* tr = tab + (size_t)x_prev[gi] * 3 * DH;
        double xr = tr[gj] + accR[reg] + (double)b_hh0[gj];
        double xz = tr[DH + gj] + accZ[reg] + (double)b_hh0[DH + gj];
        double hn_pre = accNH[reg] + (double)b_hh0[2 * DH + gj];
        float r = sigf((float)xr);
        float z = sigf((float)xz);
        float g = tanhf((float)(tr[2 * DH + gj] + (double)r * hn_pre));
        float ho = Hc[(size_t)gi * DH + gj];
        Hn[(size_t)gi * DH + gj] = (1.0f - z) * g + z * ho;
    }
}

// ---------------------------------------------------------------- layers 1/2: f64 MFMA GEMM, register-pipelined, row-indirect, swizzled
__global__ __launch_bounds__(256, 5) void layer12_mfma(const float* __restrict__ Xin,
                                                       const float* __restrict__ Hc,
                                                       float* __restrict__ Hn,
                                                       const float* __restrict__ w_ih,
                                                       const float* __restrict__ w_hh,
                                                       const float* __restrict__ b_ih,
                                                       const float* __restrict__ b_hh,
                                                       const int* __restrict__ irow_map,
                                                       const int* __restrict__ jcol_map,
                                                       const int* __restrict__ list,
                                                       const int* __restrict__ count) {
    int rt, ct_;
    swizzle_rc(blockIdx.x, rt, ct_);
    const int row0 = rt * TMR;
    const int cnt = count[0];
    if (row0 >= cnt) return;
    const int col0 = ct_ * TNC;

    __shared__ double As[TMR][BKK + 1];
    __shared__ double Bs[BKK][48 + 2];
    const int tid = threadIdx.x;
    const int lane = tid & 63, w = tid >> 6;
    const int lrow = lane & 15, lq = lane >> 4;

    int ir[4], jc[4];
    {
        const int4 a = *reinterpret_cast<const int4*>(&irow_map[lane * 4]);
        ir[0] = a.x; ir[1] = a.y; ir[2] = a.z; ir[3] = a.w;
        const int4 b = *reinterpret_cast<const int4*>(&jcol_map[lane * 4]);
        jc[0] = b.x; jc[1] = b.y; jc[2] = b.z; jc[3] = b.w;
    }

    const int ar = tid >> 2;
    const int ak = (tid & 3) * 4;
    const int arow_g = list[row0 + ar];
    const size_t arow_off = (size_t)arow_g * DH + ak;

    size_t bidx[3]; int bk_[3], bjr[3];
#pragma unroll
    for (int it = 0; it < 3; ++it) {
        const int e = it * 256 + tid;
        const int jr = e >> 4, k = e & 15;
        const int g = jr >> 4, c = jr & 15;
        bidx[it] = (size_t)(g * DH + col0 + c) * DH + k;
        bk_[it] = k; bjr[it] = jr;
    }

    d4 accR = {}, accZ = {}, accNI = {}, accNH = {};

    float4 pa = *reinterpret_cast<const float4*>(&Xin[arow_off]);
    float pb[3];
#pragma unroll
    for (int it = 0; it < 3; ++it) pb[it] = w_ih[bidx[it]];

    for (int kc2 = 0; kc2 < 64; ++kc2) {
        __syncthreads();
        As[ar][ak + 0] = (double)pa.x; As[ar][ak + 1] = (double)pa.y;
        As[ar][ak + 2] = (double)pa.z; As[ar][ak + 3] = (double)pa.w;
#pragma unroll
        for (int it = 0; it < 3; ++it) Bs[bk_[it]][bjr[it]] = (double)pb[it];
        __syncthreads();

        if (kc2 < 63) {
            const int n = kc2 + 1;
            const float* __restrict__ An = (n < 32) ? Xin : Hc;
            const float* __restrict__ Wn = (n < 32) ? w_ih : w_hh;
            const int kbn = (n & 31) * BKK;
            pa = *reinterpret_cast<const float4*>(&An[arow_off + kbn]);
#pragma unroll
            for (int it = 0; it < 3; ++it) pb[it] = Wn[bidx[it] + kbn];
        }

        if (kc2 < 32) {
#pragma unroll
            for (int s = 0; s < 4; ++s) {
                const int kk = s * 4 + lq;
                const double a = As[w * 16 + lrow][kk];
                accR = __builtin_amdgcn_mfma_f64_16x16x4f64(a, Bs[kk][ 0 + lrow], accR, 0, 0, 0);
                accZ = __builtin_amdgcn_mfma_f64_16x16x4f64(a, Bs[kk][16 + lrow], accZ, 0, 0, 0);
                accNI = __builtin_amdgcn_mfma_f64_16x16x4f64(a, Bs[kk][32 + lrow], accNI, 0, 0, 0);
            }
        } else {
#pragma unroll
            for (int s = 0; s < 4; ++s) {
                const int kk = s * 4 + lq;
                const double a = As[w * 16 + lrow][kk];
                accR = __builtin_amdgcn_mfma_f64_16x16x4f64(a, Bs[kk][ 0 + lrow], accR, 0, 0, 0);
                accZ = __builtin_amdgcn_mfma_f64_16x16x4f64(a, Bs[kk][16 + lrow], accZ, 0, 0, 0);
                accNH = __builtin_amdgcn_mfma_f64_16x16x4f64(a, Bs[kk][32 + lrow], accNH, 0, 0, 0);
            }
        }
    }

#pragma unroll
    for (int reg = 0; reg < 4; ++reg) {
        const int gi = list[row0 + w * 16 + ir[reg]];
        const int gj = col0 + jc[reg];
        double xr = accR[reg] + (double)b_ih[gj] + (double)b_hh[gj];
        double xz = accZ[reg] + (double)b_ih[DH + gj] + (double)b_hh[DH + gj];
        double xi = accNI[reg] + (double)b_ih[2 * DH + gj];
        double hn_pre = accNH[reg] + (double)b_hh[2 * DH + gj];
        float r = sigf((float)xr);
        float z = sigf((float)xz);
        float g = tanhf((float)(xi + (double)r * hn_pre));
        float ho = Hc[(size_t)gi * DH + gj];
        Hn[(size_t)gi * DH + gj] = (1.0f - z) * g + z * ho;
    }
}

// ---------------------------------------------------------------- logits + fp32 softmax + argmax + token update (row-indirect)
__global__ __launch_bounds__(256) void logits_kernel(const float* __restrict__ H2,
                                                     const float* __restrict__ h2v_w,
                                                     const float* __restrict__ h2v_b,
                                                     int* __restrict__ x_prev,
                                                     int* __restrict__ eos,
                                                     int* __restrict__ out,
                                                     const int* __restrict__ list,
                                                     const int* __restrict__ count,
                                                     int t) {
    const int rowbase = blockIdx.x * 16;
    const int cnt = count[0];
    if (rowbase >= cnt) return;

    __shared__ float Ws[VOCAB][65];
    __shared__ float Hs[16][65];
    const int tid = threadIdx.x;
    double acc[4] = {0.0, 0.0, 0.0, 0.0};

    for (int k0 = 0; k0 < DH; k0 += 64) {
        __syncthreads();
#pragma unroll
        for (int it = 0; it < 16; ++it) {
            int idx = tid + 256 * it;
            int v = idx >> 6, k = idx & 63;
            Ws[v][k] = h2v_w[(size_t)v * DH + k0 + k];
        }
#pragma unroll
        for (int it = 0; it < 4; ++it) {
            int idx = tid + 256 * it;
            int r = idx >> 6, k = idx & 63;
            Hs[r][k] = H2[(size_t)list[rowbase + r] * DH + k0 + k];
        }
        __syncthreads();
        const int r = tid >> 4;
        const int vb = (tid & 15) * 4;
#pragma unroll 16
        for (int k = 0; k < 64; ++k) {
            double h = (double)Hs[r][k];
            acc[0] += h * (double)Ws[vb + 0][k];
            acc[1] += h * (double)Ws[vb + 1][k];
            acc[2] += h * (double)Ws[vb + 2][k];
            acc[3] += h * (double)Ws[vb + 3][k];
        }
    }

    const int r = tid >> 4;
    const int vb = (tid & 15) * 4;
    float lf[4];
#pragma unroll
    for (int vv = 0; vv < 4; ++vv) lf[vv] = (float)(acc[vv] + (double)h2v_b[vb + vv]);

    float m = fmaxf(fmaxf(lf[0], lf[1]), fmaxf(lf[2], lf[3]));
#pragma unroll
    for (int off = 1; off < 16; off <<= 1) m = fmaxf(m, __shfl_xor(m, off));
    float e[4];
    float ssum = 0.f;
#pragma unroll
    for (int vv = 0; vv < 4; ++vv) { e[vv] = expf(lf[vv] - m); ssum += e[vv]; }
#pragma unroll
    for (int off = 1; off < 16; off <<= 1) ssum += __shfl_xor(ssum, off);

    float best = e[0] / ssum;
    int bi = vb;
#pragma unroll
    for (int vv = 1; vv < 4; ++vv) {
        float pv = e[vv] / ssum;
        if (pv > best) { best = pv; bi = vb + vv; }
    }
#pragma unroll
    for (int off = 1; off < 16; off <<= 1) {
        float ov = __shfl_xor(best, off);
        int oi = __shfl_xor(bi, off);
        if (ov > best || (ov == best && oi < bi)) { best = ov; bi = oi; }
    }
    if ((tid & 15) == 0) {
        const int gi = list[rowbase + r];
        const int ee = eos[gi];
        const int xt = bi;
        out[(size_t)gi * TMAX + t] = ee ? 0 : xt;
        if (!ee && xt == EOS_TOK) {
            out[NSEQ * TMAX + gi] = t + 1;
            eos[gi] = 1;
        }
        x_prev[gi] = xt;
    }
}

// ---------------------------------------------------------------- host
extern "C" void kernel_launch(void* const* d_in, const int* in_sizes, int n_in,
                              void* d_out, int out_size, void* d_ws, size_t ws_size,
                              hipStream_t stream) {
    const float* Z        = (const float*)d_in[0];
    const float* emb      = (const float*)d_in[1];
    const float* z2h_w    = (const float*)d_in[2];
    const float* z2h_b    = (const float*)d_in[3];
    const float* w_ih0    = (const float*)d_in[4];
    const float* w_ih_rest= (const float*)d_in[5];   // [2][1536][512]
    const float* w_hh     = (const float*)d_in[6];   // [3][1536][512]
    const float* b_ih     = (const float*)d_in[7];   // [3][1536]
    const float* b_hh     = (const float*)d_in[8];
    const float* h2v_w    = (const float*)d_in[9];
    const float* h2v_b    = (const float*)d_in[10];

    int* out = (int*)d_out;
    char* ws = (char*)d_ws;
    const size_t HB = (size_t)NSEQ * DH * sizeof(float);   // 16 MiB per H buffer
    float* B[4] = {(float*)ws, (float*)(ws + HB), (float*)(ws + 2 * HB), (float*)(ws + 3 * HB)};
    double* tab = (double*)(ws + 4 * HB);                  // [64][1536] fp64
    int* x_prev = (int*)(ws + 4 * HB + (size_t)VOCAB * 3 * DH * sizeof(double));
    int* eos    = x_prev + NSEQ;
    int* irow_map = eos + NSEQ;      // [64][4]
    int* jcol_map = irow_map + 256;  // [64][4]
    int* alist    = jcol_map + 256;  // [8192] active row list
    int* acount   = alist + NSEQ;    // [1]

    // PAD-fill the token region so skipped (post-EOS) rows read as PAD=0.
    hipMemsetAsync(out, 0, (size_t)NSEQ * TMAX * sizeof(int), stream);
    init_kernel<<<NSEQ / 256, 256, 0, stream>>>(x_prev, eos, out, alist, acount);
    probe_kernel<<<1, 64, 0, stream>>>(irow_map, jcol_map);
    h0_kernel<<<NSEQ, 256, 0, stream>>>(Z, z2h_w, z2h_b, B[0], B[1], B[2]);
    gi0_kernel<<<VOCAB, 256, 0, stream>>>(emb, w_ih0, b_ih, tab);

    const size_t WSTRIDE = (size_t)3 * DH * DH;   // 1536*512
    int c0 = 0, c1 = 1, c2 = 2, sp = 3;
    const int lgrid = (NSEQ / TMR) * (DH / TNC);  // 4096 blocks, 1-D swizzled
    for (int t = 1; t < TMAX; ++t) {
        layer0_mfma<<<lgrid, 256, 0, stream>>>(B[c0], B[sp], w_hh, b_hh, tab, x_prev,
                                               irow_map, jcol_map, alist, acount);
        layer12_mfma<<<lgrid, 256, 0, stream>>>(B[sp], B[c1], B[c0],
            w_ih_rest, w_hh + WSTRIDE, b_ih + 3 * DH, b_hh + 3 * DH,
            irow_map, jcol_map, alist, acount);
        layer12_mfma<<<lgrid, 256, 0, stream>>>(B[c0], B[c2], B[c1],
            w_ih_rest + WSTRIDE, w_hh + 2 * WSTRIDE, b_ih + 6 * DH, b_hh + 6 * DH,
            irow_map, jcol_map, alist, acount);
        logits_kernel<<<NSEQ / 16, 256, 0, stream>>>(B[c1], h2v_w, h2v_b, x_prev, eos, out,
                                                     alist, acount, t);
        if (t < TMAX - 1)
            compact_kernel<<<1, 1024, 0, stream>>>(eos, alist, acount);
        int n0 = sp, n1 = c0, n2 = c1, nsp = c2;
        c0 = n0; c1 = n1; c2 = n2; sp = nsp;
    }
}